// Round 6
// baseline (3959.290 us; speedup 1.0000x reference)
//
#include <hip/hip_runtime.h>

// Problem constants
#define EDIM 256
#define SLEN 64
#define TLEN 512
#define NT 1024
#define NWAVES 16
#define JH 128            // j-half (gate rows per role)
#define WA_ROWS 640       // 256 (Ww rows) + 384 (whh own-gate rows)
#define GX_ROWS 384

// ---- fused pack prepass (verified rounds 3-5) ----
// z in [0,6):  whh role/gate slices -> WA[role][k][256 + g*128 + j] = whh[g*256+role*128+j][k]
// z in [6,12): wih role/gate slices -> wihT[role][k][g*128 + j]     = wih[g*256+role*128+j][k]
// z in [12,14): Ww for role z-12    -> WA[role][k][j]               = Ww[j][k]
__global__ __launch_bounds__(256) void pack_fused_kernel(
    const float* __restrict__ Ww, const float* __restrict__ whh,
    const float* __restrict__ wih, float* __restrict__ WA, float* __restrict__ wihT)
{
    const int z = blockIdx.z;
    const float* in; float* out; int R, C, ostride, ooff;
    if (z < 12) {
        int mat = z / 6, rem = z % 6, role = rem / 3, g = rem % 3;
        if (mat == 0) {
            in = whh + (size_t)(g * 256 + role * JH) * 256; C = 256;
            out = WA + (size_t)role * 256 * WA_ROWS; ostride = WA_ROWS; ooff = 256 + g * JH; R = JH;
        } else {
            in = wih + (size_t)(g * 256 + role * JH) * 512; C = 512;
            out = wihT + (size_t)role * 512 * GX_ROWS; ostride = GX_ROWS; ooff = g * JH; R = JH;
        }
    } else {
        int role = z - 12; in = Ww; C = 256;
        out = WA + (size_t)role * 256 * WA_ROWS; ostride = WA_ROWS; ooff = 0; R = 256;
    }
    const int r0 = blockIdx.y * 64, c0 = blockIdx.x * 64;
    if (r0 >= R || c0 >= C) return;
    __shared__ float tile[64][65];
    for (int i = threadIdx.x; i < 64 * 64; i += 256) {
        int r = i >> 6, c = i & 63;
        tile[r][c] = in[(size_t)(r0 + r) * C + (c0 + c)];
    }
    __syncthreads();
    for (int i = threadIdx.x; i < 64 * 64; i += 256) {
        int c = i >> 6, r = i & 63;
        out[(size_t)(c0 + c) * ostride + ooff + (r0 + r)] = tile[r][c];
    }
}

__global__ __launch_bounds__(NT) void gru_decoder_kernel(
    const float* __restrict__ signal,   // [B,T,E]
    const float* __restrict__ bases,    // [B,S,E]
    const int* __restrict__ mask,       // [B,T]
    const float* __restrict__ WA,       // [2][256k][640r]
    const float* __restrict__ Wb,
    const float* __restrict__ lng, const float* __restrict__ lnb,
    const float* __restrict__ wihT,     // [2][512k][384r]
    const float* __restrict__ bih, const float* __restrict__ bhh,
    const float* __restrict__ hinit,
    unsigned long long* __restrict__ payload,  // [B][2 parity][2 role][128] tagged words
    float* __restrict__ out, int nb, int never)
{
    const int bid  = blockIdx.x;
    const int pair = bid % nb;          // batch index
    const int role = bid / nb;
    const int b    = pair;
    const int joff = role * JH;
    const int tid  = threadIdx.x;
    const int lane = tid & 63;
    const int wv   = tid >> 6;

    __shared__ float h_s[EDIM];
    __shared__ float wap[4 * WA_ROWS];        // A1 partials: rows 0..255 v, 256..639 gh_own (live to gates)
    __shared__ float ctxp[NWAVES * EDIM];
    __shared__ float mw_s[NWAVES], lw_s[NWAVES];
    __shared__ float inp_s[2 * EDIM], inpn_s[2 * EDIM];
    __shared__ float gxp[8 * GX_ROWS];
    __shared__ float embias_s[TLEN];
    __shared__ float scr2[2 * NWAVES];
    __shared__ float sWb[EDIM], sbih[768], sbhh[768], slng[512], slnb[512];
    __shared__ float pad_lds[8 * 1024];       // occupancy limiter -> 1 block/CU (co-residency)
    if (never) { pad_lds[tid] = (float)never; h_s[0] = pad_lds[(tid + 1) & 8191]; }

    const float* WAr   = WA   + (size_t)role * 256 * WA_ROWS;
    const float* wihTr = wihT + (size_t)role * 512 * GX_ROWS;
    const float* sigb  = signal + (size_t)b * TLEN * EDIM;
    const int*   maskb = mask + (size_t)b * TLEN;

    unsigned long long* pbuf = payload + (size_t)pair * 512;

    if (tid < 256) { h_s[tid] = hinit[tid]; sWb[tid] = Wb[tid]; }
    if (tid < 512) { embias_s[tid] = maskb[tid] ? -1e30f : 0.0f; slng[tid] = lng[tid]; slnb[tid] = lnb[tid]; }
    if (tid < 768) { sbih[tid] = bih[tid]; sbhh[tid] = bhh[tid]; }
    // pre-publish hinit own-half with tag 1 into parity-1 slot (consumed by partner at s=0)
    if (tid < JH) {
        unsigned long long w0 = (1ULL << 32) | (unsigned long long)__float_as_uint(hinit[joff + tid]);
        __hip_atomic_store(pbuf + 256 + role * JH + tid, w0, __ATOMIC_RELAXED, __HIP_MEMORY_SCOPE_AGENT);
    }
    __syncthreads();

    for (int s = 0; s < SLEN; ++s) {
        // ---- A1: [v; gh_own] = WA_role @ h. 4-way k-split, q WAVE-UNIFORM (tid>>8).
        //      k-chunk remap: q<2 -> OWN h-half (in h_s from gates), q>=2 -> PARTNER half
        //      (spin-consumed from tagged payload; spin overlaps q<2 streaming).
        {
            const int q = tid >> 8;             // 0..3 wave-uniform
            const int w = tid & 255;
            const int kbase = (q < 2) ? (joff + q * 64) : ((JH - joff) + (q - 2) * 64);

            float hld = 0.f;
            if (q >= 2) {
                // lane l spin-loads partner h element kbase+l (tag >= s+1)
                const unsigned long long* cslot = pbuf + ((s + 1) & 1) * 256 + (1 - role) * JH;
                const unsigned int want = (unsigned int)(s + 1);
                const unsigned long long* ap = cslot + (q - 2) * 64 + lane;
                unsigned long long pw = __hip_atomic_load(ap, __ATOMIC_RELAXED, __HIP_MEMORY_SCOPE_AGENT);
                while ((unsigned int)(pw >> 32) < want) {
                    __builtin_amdgcn_s_sleep(1);
                    pw = __hip_atomic_load(ap, __ATOMIC_RELAXED, __HIP_MEMORY_SCOPE_AGENT);
                }
                hld = __uint_as_float((unsigned int)pw);
            }

            if (w < 160) {
                const int r4 = w * 4;           // 0..636
                const float* base = WAr + (size_t)kbase * WA_ROWS + r4;
                float a0 = 0.f, a1 = 0.f, a2 = 0.f, a3 = 0.f;
                if (q < 2) {
                    const float* xk = &h_s[kbase];
#pragma unroll 8
                    for (int k = 0; k < 64; ++k) {
                        float4 w4 = *reinterpret_cast<const float4*>(base + (size_t)k * WA_ROWS);
                        float x = xk[k];
                        a0 += w4.x * x; a1 += w4.y * x; a2 += w4.z * x; a3 += w4.w * x;
                    }
                } else {
#pragma unroll
                    for (int k = 0; k < 64; ++k) {
                        float4 w4 = *reinterpret_cast<const float4*>(base + (size_t)k * WA_ROWS);
                        // readlane: exec-independent broadcast of lane k's hld
                        float x = __uint_as_float(__builtin_amdgcn_readlane(__float_as_uint(hld), k));
                        a0 += w4.x * x; a1 += w4.y * x; a2 += w4.z * x; a3 += w4.w * x;
                    }
                }
                float4 acc; acc.x = a0; acc.y = a1; acc.z = a2; acc.w = a3;
                *reinterpret_cast<float4*>(&wap[q * WA_ROWS + r4]) = acc;
            } else if (q < 2) {
                // spares in q<2 prefetch x (bases) as float2
                const int sp = q * 96 + (w - 160);   // 0..191
                if (sp < 128) {
                    float2 x2 = *reinterpret_cast<const float2*>(
                        bases + ((size_t)b * SLEN + s) * EDIM + sp * 2);
                    inp_s[sp * 2]     = x2.x;
                    inp_s[sp * 2 + 1] = x2.y;
                }
            }
        }
        __syncthreads();                        // (1) wap + inp_s[0..255] ready

        // ---- Attention over full T=512 (duplicated across pair), v folded from wap.
        //      Wave owns 32 consecutive t; lane owns e-slice [lane*4, lane*4+4).
        {
            float4 wb = *reinterpret_cast<const float4*>(&sWb[lane * 4]);
            float4 p0 = *reinterpret_cast<const float4*>(&wap[0 * WA_ROWS + lane * 4]);
            float4 p1 = *reinterpret_cast<const float4*>(&wap[1 * WA_ROWS + lane * 4]);
            float4 p2 = *reinterpret_cast<const float4*>(&wap[2 * WA_ROWS + lane * 4]);
            float4 p3 = *reinterpret_cast<const float4*>(&wap[3 * WA_ROWS + lane * 4]);
            float4 v4;
            v4.x = wb.x + p0.x + p1.x + p2.x + p3.x;
            v4.y = wb.y + p0.y + p1.y + p2.y + p3.y;
            v4.z = wb.z + p0.z + p1.z + p2.z + p3.z;
            v4.w = wb.w + p0.w + p1.w + p2.w + p3.w;

            float m = -3e38f, l = 0.f;
            float c0 = 0.f, c1 = 0.f, c2 = 0.f, c3 = 0.f;
            const int t0 = wv * 32;
#pragma unroll 4
            for (int i = 0; i < 32; i += 2) {
                const int ta = t0 + i, tb = ta + 1;
                float4 A  = *reinterpret_cast<const float4*>(sigb + (size_t)ta * EDIM + lane * 4);
                float4 Bv = *reinterpret_cast<const float4*>(sigb + (size_t)tb * EDIM + lane * 4);
                float da = A.x * v4.x + A.y * v4.y + A.z * v4.z + A.w * v4.w;
                float db = Bv.x * v4.x + Bv.y * v4.y + Bv.z * v4.z + Bv.w * v4.w;
#pragma unroll
                for (int mk = 32; mk > 0; mk >>= 1) {
                    da += __shfl_xor(da, mk, 64);
                    db += __shfl_xor(db, mk, 64);
                }
                float ea = da + embias_s[ta];
                float eb = db + embias_s[tb];
                float mn = fmaxf(m, fmaxf(ea, eb));
                float sc = __expf(m - mn);
                float pa = __expf(ea - mn);
                float pb = __expf(eb - mn);
                l  = l  * sc + pa + pb;
                c0 = c0 * sc + pa * A.x + pb * Bv.x;
                c1 = c1 * sc + pa * A.y + pb * Bv.y;
                c2 = c2 * sc + pa * A.z + pb * Bv.z;
                c3 = c3 * sc + pa * A.w + pb * Bv.w;
                m = mn;
            }
            if (lane == 0) { mw_s[wv] = m; lw_s[wv] = l; }
            float4 cc; cc.x = c0; cc.y = c1; cc.z = c2; cc.w = c3;
            *reinterpret_cast<float4*>(&ctxp[wv * EDIM + lane * 4]) = cc;
        }
        __syncthreads();                        // (2) ctxp/mw/lw ready

        // ---- inp build: ews folded (redundant M + 16 exps per thread) ----
        if (tid < EDIM) {
            float M = mw_s[0];
#pragma unroll
            for (int w = 1; w < NWAVES; ++w) M = fmaxf(M, mw_s[w]);
            float L = 0.f, c = 0.f;
#pragma unroll
            for (int w = 0; w < NWAVES; ++w) {
                float ew = __expf(mw_s[w] - M);
                L += lw_s[w] * ew;
                c += ctxp[w * EDIM + tid] * ew;
            }
            inp_s[EDIM + tid] = c / L;
        }
        __syncthreads();                        // (3) inp ready

        // ---- LayerNorm over 2E=512, single pass ----
        {
            float val = (tid < 2 * EDIM) ? inp_s[tid] : 0.f;
            float s1 = val, s2 = val * val;
#pragma unroll
            for (int mk = 32; mk > 0; mk >>= 1) {
                s1 += __shfl_xor(s1, mk, 64);
                s2 += __shfl_xor(s2, mk, 64);
            }
            if (lane == 0) { scr2[wv] = s1; scr2[NWAVES + wv] = s2; }
            __syncthreads();                    // (4)
            float S1 = 0.f, S2 = 0.f;
#pragma unroll
            for (int w = 0; w < NWAVES; ++w) { S1 += scr2[w]; S2 += scr2[NWAVES + w]; }
            float mu  = S1 * (1.0f / (2 * EDIM));
            float var = S2 * (1.0f / (2 * EDIM)) - mu * mu;
            float rs  = rsqrtf(var + 1e-5f);
            if (tid < 2 * EDIM) inpn_s[tid] = (val - mu) * rs * slng[tid] + slnb[tid];
        }
        __syncthreads();                        // (5) inpn ready

        // ---- GX: gx_own = wih_own @ inpn (384x512). 8-way k-split, q WAVE-UNIFORM. ----
        {
            const int q = tid >> 7;             // 0..7 wave-uniform
            const int w = tid & 127;
            if (w < 96) {
                const int r4 = w * 4;           // 0..380
                const float* base = wihTr + (size_t)(q * 64) * GX_ROWS + r4;
                const float* xk = &inpn_s[q * 64];
                float a0 = 0.f, a1 = 0.f, a2 = 0.f, a3 = 0.f;
#pragma unroll 8
                for (int k = 0; k < 64; ++k) {
                    float4 w4 = *reinterpret_cast<const float4*>(base + (size_t)k * GX_ROWS);
                    float x = xk[k];
                    a0 += w4.x * x; a1 += w4.y * x; a2 += w4.z * x; a3 += w4.w * x;
                }
                float4 acc; acc.x = a0; acc.y = a1; acc.z = a2; acc.w = a3;
                *reinterpret_cast<float4*>(&gxp[q * GX_ROWS + r4]) = acc;
            }
        }
        __syncthreads();                        // (6) gxp ready

        // ---- gates for own j-half (torch order r,z,n) + tagged publish (tag s+2) ----
        {
            unsigned long long* myslot = pbuf + (s & 1) * 256 + role * JH;
            if (tid < JH) {
                const int jl = tid, j = joff + jl;
                float xr = sbih[j], xz = sbih[EDIM + j], xn = sbih[2 * EDIM + j];
#pragma unroll
                for (int q = 0; q < 8; ++q) {
                    xr += gxp[q * GX_ROWS + jl];
                    xz += gxp[q * GX_ROWS + JH + jl];
                    xn += gxp[q * GX_ROWS + 2 * JH + jl];
                }
                float hr = sbhh[j], hz = sbhh[EDIM + j], hn_ = sbhh[2 * EDIM + j];
#pragma unroll
                for (int q = 0; q < 4; ++q) {
                    hr  += wap[q * WA_ROWS + 256 + jl];
                    hz  += wap[q * WA_ROWS + 384 + jl];
                    hn_ += wap[q * WA_ROWS + 512 + jl];
                }
                float r = 1.0f / (1.0f + __expf(-(xr + hr)));
                float z = 1.0f / (1.0f + __expf(-(xz + hz)));
                float n = tanhf(xn + r * hn_);
                float hnew = (1.0f - z) * n + z * h_s[j];
                h_s[j] = hnew;
                out[((size_t)b * SLEN + s) * EDIM + j] = hnew;

                unsigned long long wrd = ((unsigned long long)(unsigned int)(s + 2) << 32)
                                       | (unsigned long long)__float_as_uint(hnew);
                __hip_atomic_store(myslot + jl, wrd, __ATOMIC_RELAXED, __HIP_MEMORY_SCOPE_AGENT);
            }
        }
        __syncthreads();                        // (7) h_s own-half ready for next A1
    }
}

extern "C" void kernel_launch(void* const* d_in, const int* in_sizes, int n_in,
                              void* d_out, int out_size, void* d_ws, size_t ws_size,
                              hipStream_t stream) {
    const float* signal = (const float*)d_in[0];
    const float* bases  = (const float*)d_in[1];
    const int*   mask   = (const int*)d_in[2];
    const float* Ww     = (const float*)d_in[3];
    const float* Wb     = (const float*)d_in[4];
    const float* lng    = (const float*)d_in[5];
    const float* lnb    = (const float*)d_in[6];
    const float* wih    = (const float*)d_in[7];
    const float* bih    = (const float*)d_in[8];
    const float* whh    = (const float*)d_in[9];
    const float* bhh    = (const float*)d_in[10];
    const float* hinit  = (const float*)d_in[11];
    float*       out    = (float*)d_out;

    const int B = in_sizes[0] / (TLEN * EDIM);   // 128

    // workspace: WA[2][256][640] | wihT[2][512][384] | payload u64[B][512]  (~3.4 MB)
    float* WA   = (float*)d_ws;
    float* wihT = WA + 2 * 256 * WA_ROWS;
    unsigned long long* payload = (unsigned long long*)(wihT + 2 * 512 * GX_ROWS);

    hipMemsetAsync(payload, 0, (size_t)B * 512 * sizeof(unsigned long long), stream);
    pack_fused_kernel<<<dim3(8, 4, 14), 256, 0, stream>>>(Ww, whh, wih, WA, wihT);
    gru_decoder_kernel<<<dim3(2 * B), dim3(NT), 0, stream>>>(
        signal, bases, mask, WA, Wb, lng, lnb, wihT, bih, bhh, hinit, payload, out, B, 0);
}

// Round 7
// 2094.532 us; speedup vs baseline: 1.8903x; 1.8903x over previous
//
#include <hip/hip_runtime.h>

// Problem constants
#define EDIM 256
#define SLEN 64
#define TLEN 512
#define NT 1024
#define NWAVES 16
#define JH 128            // j-half (gate rows per role)
#define WA_ROWS 640       // 256 (Ww rows) + 384 (whh own-gate rows)
#define GX_ROWS 384

// ---- fused pack prepass (verified rounds 3-6) ----
// z in [0,6):  whh role/gate slices -> WA[role][k][256 + g*128 + j] = whh[g*256+role*128+j][k]
// z in [6,12): wih role/gate slices -> wihT[role][k][g*128 + j]     = wih[g*256+role*128+j][k]
// z in [12,14): Ww for role z-12    -> WA[role][k][j]               = Ww[j][k]
__global__ __launch_bounds__(256) void pack_fused_kernel(
    const float* __restrict__ Ww, const float* __restrict__ whh,
    const float* __restrict__ wih, float* __restrict__ WA, float* __restrict__ wihT)
{
    const int z = blockIdx.z;
    const float* in; float* out; int R, C, ostride, ooff;
    if (z < 12) {
        int mat = z / 6, rem = z % 6, role = rem / 3, g = rem % 3;
        if (mat == 0) {
            in = whh + (size_t)(g * 256 + role * JH) * 256; C = 256;
            out = WA + (size_t)role * 256 * WA_ROWS; ostride = WA_ROWS; ooff = 256 + g * JH; R = JH;
        } else {
            in = wih + (size_t)(g * 256 + role * JH) * 512; C = 512;
            out = wihT + (size_t)role * 512 * GX_ROWS; ostride = GX_ROWS; ooff = g * JH; R = JH;
        }
    } else {
        int role = z - 12; in = Ww; C = 256;
        out = WA + (size_t)role * 256 * WA_ROWS; ostride = WA_ROWS; ooff = 0; R = 256;
    }
    const int r0 = blockIdx.y * 64, c0 = blockIdx.x * 64;
    if (r0 >= R || c0 >= C) return;
    __shared__ float tile[64][65];
    for (int i = threadIdx.x; i < 64 * 64; i += 256) {
        int r = i >> 6, c = i & 63;
        tile[r][c] = in[(size_t)(r0 + r) * C + (c0 + c)];
    }
    __syncthreads();
    for (int i = threadIdx.x; i < 64 * 64; i += 256) {
        int c = i >> 6, r = i & 63;
        out[(size_t)(c0 + c) * ostride + ooff + (r0 + r)] = tile[r][c];
    }
}

__global__ __launch_bounds__(NT) void gru_decoder_kernel(
    const float* __restrict__ signal,   // [B,T,E]
    const float* __restrict__ bases,    // [B,S,E]
    const int* __restrict__ mask,       // [B,T]
    const float* __restrict__ WA,       // [2][256k][640r]
    const float* __restrict__ Wb,
    const float* __restrict__ lng, const float* __restrict__ lnb,
    const float* __restrict__ wihT,     // [2][512k][384r]
    const float* __restrict__ bih, const float* __restrict__ bhh,
    const float* __restrict__ hinit,
    unsigned long long* __restrict__ payload,  // [B][2 parity][2 role][128] tagged words
    float* __restrict__ out, int nb, int never)
{
    const int bid  = blockIdx.x;
    const int pair = bid % nb;          // batch index (roles p and p+nb share an XCD)
    const int role = bid / nb;
    const int b    = pair;
    const int joff = role * JH;
    const int tid  = threadIdx.x;
    const int lane = tid & 63;
    const int wv   = tid >> 6;

    __shared__ float h_s[EDIM];
    __shared__ float wap[4 * WA_ROWS];        // A1 partials: rows 0..255 v, 256..639 gh_own (live to gates)
    __shared__ float ctxp[NWAVES * EDIM];
    __shared__ float mw_s[NWAVES], lw_s[NWAVES];
    __shared__ float inp_s[2 * EDIM], inpn_s[2 * EDIM];
    __shared__ float gxp[8 * GX_ROWS];
    __shared__ float embias_s[TLEN];
    __shared__ float scr2[2 * NWAVES];
    __shared__ float sWb[EDIM], sbih[768], sbhh[768], slng[512], slnb[512];
    __shared__ float pad_lds[8 * 1024];       // occupancy limiter -> 1 block/CU (co-residency)
    if (never) { pad_lds[tid] = (float)never; h_s[0] = pad_lds[(tid + 1) & 8191]; }

    const float* WAr   = WA   + (size_t)role * 256 * WA_ROWS;
    const float* wihTr = wihT + (size_t)role * 512 * GX_ROWS;
    const float* sigb  = signal + (size_t)b * TLEN * EDIM;
    const int*   maskb = mask + (size_t)b * TLEN;

    unsigned long long* pbuf = payload + (size_t)pair * 512;

    if (tid < 256) { h_s[tid] = hinit[tid]; sWb[tid] = Wb[tid]; }
    if (tid < 512) { embias_s[tid] = maskb[tid] ? -1e30f : 0.0f; slng[tid] = lng[tid]; slnb[tid] = lnb[tid]; }
    if (tid < 768) { sbih[tid] = bih[tid]; sbhh[tid] = bhh[tid]; }
    __syncthreads();

    for (int s = 0; s < SLEN; ++s) {
        // ---- A1: [v; gh_own] = WA_role @ h. 4-way k-split, q WAVE-UNIFORM (tid>>8).
        //      Within q-group: workers w<160 own 4 rows (float4, contiguous 1KB/wave).
        //      Idle workers (w>=160) prefetch x into inp_s[0..255].
        {
            const int q = tid >> 8;             // 0..3 wave-uniform
            const int w = tid & 255;
            if (w < 160) {
                const int r4 = w * 4;           // 0..636
                const float* base = WAr + (size_t)(q * 64) * WA_ROWS + r4;
                const float* xk = &h_s[q * 64];
                float a0 = 0.f, a1 = 0.f, a2 = 0.f, a3 = 0.f;
#pragma unroll 8
                for (int k = 0; k < 64; ++k) {
                    float4 w4 = *reinterpret_cast<const float4*>(base + (size_t)k * WA_ROWS);
                    float x = xk[k];
                    a0 += w4.x * x; a1 += w4.y * x; a2 += w4.z * x; a3 += w4.w * x;
                }
                float4 acc; acc.x = a0; acc.y = a1; acc.z = a2; acc.w = a3;
                *reinterpret_cast<float4*>(&wap[q * WA_ROWS + r4]) = acc;
            } else {
                const int li = q * 96 + (w - 160);   // 0..383
                if (li < 256) inp_s[li] = bases[((size_t)b * SLEN + s) * EDIM + li];
            }
        }
        __syncthreads();                        // (1) wap + inp_s[0..255] ready

        // ---- Attention over full T=512 (duplicated across pair), v FOLDED from wap.
        //      Wave owns 32 consecutive t; lane owns e-slice [lane*4, lane*4+4).
        {
            float4 wb = *reinterpret_cast<const float4*>(&sWb[lane * 4]);
            float4 p0 = *reinterpret_cast<const float4*>(&wap[0 * WA_ROWS + lane * 4]);
            float4 p1 = *reinterpret_cast<const float4*>(&wap[1 * WA_ROWS + lane * 4]);
            float4 p2 = *reinterpret_cast<const float4*>(&wap[2 * WA_ROWS + lane * 4]);
            float4 p3 = *reinterpret_cast<const float4*>(&wap[3 * WA_ROWS + lane * 4]);
            float4 v4;
            v4.x = wb.x + p0.x + p1.x + p2.x + p3.x;
            v4.y = wb.y + p0.y + p1.y + p2.y + p3.y;
            v4.z = wb.z + p0.z + p1.z + p2.z + p3.z;
            v4.w = wb.w + p0.w + p1.w + p2.w + p3.w;

            float m = -3e38f, l = 0.f;
            float c0 = 0.f, c1 = 0.f, c2 = 0.f, c3 = 0.f;
            const int t0 = wv * 32;
#pragma unroll 4
            for (int i = 0; i < 32; i += 2) {
                const int ta = t0 + i, tb = ta + 1;
                float4 A  = *reinterpret_cast<const float4*>(sigb + (size_t)ta * EDIM + lane * 4);
                float4 Bv = *reinterpret_cast<const float4*>(sigb + (size_t)tb * EDIM + lane * 4);
                float da = A.x * v4.x + A.y * v4.y + A.z * v4.z + A.w * v4.w;
                float db = Bv.x * v4.x + Bv.y * v4.y + Bv.z * v4.z + Bv.w * v4.w;
#pragma unroll
                for (int mk = 32; mk > 0; mk >>= 1) {
                    da += __shfl_xor(da, mk, 64);
                    db += __shfl_xor(db, mk, 64);
                }
                float ea = da + embias_s[ta];
                float eb = db + embias_s[tb];
                float mn = fmaxf(m, fmaxf(ea, eb));
                float sc = __expf(m - mn);
                float pa = __expf(ea - mn);
                float pb = __expf(eb - mn);
                l  = l  * sc + pa + pb;
                c0 = c0 * sc + pa * A.x + pb * Bv.x;
                c1 = c1 * sc + pa * A.y + pb * Bv.y;
                c2 = c2 * sc + pa * A.z + pb * Bv.z;
                c3 = c3 * sc + pa * A.w + pb * Bv.w;
                m = mn;
            }
            if (lane == 0) { mw_s[wv] = m; lw_s[wv] = l; }
            float4 cc; cc.x = c0; cc.y = c1; cc.z = c2; cc.w = c3;
            *reinterpret_cast<float4*>(&ctxp[wv * EDIM + lane * 4]) = cc;
        }
        __syncthreads();                        // (2) ctxp/mw/lw ready

        // ---- inp build: ews FOLDED (redundant M + 16 exps per thread) ----
        if (tid < EDIM) {
            float M = mw_s[0];
#pragma unroll
            for (int w = 1; w < NWAVES; ++w) M = fmaxf(M, mw_s[w]);
            float L = 0.f, c = 0.f;
#pragma unroll
            for (int w = 0; w < NWAVES; ++w) {
                float ew = __expf(mw_s[w] - M);
                L += lw_s[w] * ew;
                c += ctxp[w * EDIM + tid] * ew;
            }
            inp_s[EDIM + tid] = c / L;
        }
        __syncthreads();                        // (3) inp ready (x half loaded in A1)

        // ---- LayerNorm over 2E=512, single pass ----
        {
            float val = (tid < 2 * EDIM) ? inp_s[tid] : 0.f;
            float s1 = val, s2 = val * val;
#pragma unroll
            for (int mk = 32; mk > 0; mk >>= 1) {
                s1 += __shfl_xor(s1, mk, 64);
                s2 += __shfl_xor(s2, mk, 64);
            }
            if (lane == 0) { scr2[wv] = s1; scr2[NWAVES + wv] = s2; }
            __syncthreads();                    // (4)
            float S1 = 0.f, S2 = 0.f;
#pragma unroll
            for (int w = 0; w < NWAVES; ++w) { S1 += scr2[w]; S2 += scr2[NWAVES + w]; }
            float mu  = S1 * (1.0f / (2 * EDIM));
            float var = S2 * (1.0f / (2 * EDIM)) - mu * mu;
            float rs  = rsqrtf(var + 1e-5f);
            if (tid < 2 * EDIM) inpn_s[tid] = (val - mu) * rs * slng[tid] + slnb[tid];
        }
        __syncthreads();                        // (5) inpn ready

        // ---- GX: gx_own = wih_own @ inpn (384x512). 8-way k-split, q WAVE-UNIFORM. ----
        {
            const int q = tid >> 7;             // 0..7 wave-uniform
            const int w = tid & 127;
            if (w < 96) {
                const int r4 = w * 4;           // 0..380
                const float* base = wihTr + (size_t)(q * 64) * GX_ROWS + r4;
                const float* xk = &inpn_s[q * 64];
                float a0 = 0.f, a1 = 0.f, a2 = 0.f, a3 = 0.f;
#pragma unroll 8
                for (int k = 0; k < 64; ++k) {
                    float4 w4 = *reinterpret_cast<const float4*>(base + (size_t)k * GX_ROWS);
                    float x = xk[k];
                    a0 += w4.x * x; a1 += w4.y * x; a2 += w4.z * x; a3 += w4.w * x;
                }
                float4 acc; acc.x = a0; acc.y = a1; acc.z = a2; acc.w = a3;
                *reinterpret_cast<float4*>(&gxp[q * GX_ROWS + r4]) = acc;
            }
        }
        __syncthreads();                        // (6) gxp ready

        // ---- gates for own j-half (torch order r,z,n) + tagged-word h exchange ----
        // Compact round-5 protocol: 128 threads publish (tag s+1) then spin for partner.
        {
            unsigned long long* myslot = pbuf + (s & 1) * 256 + role * JH;
            unsigned long long* pslot  = pbuf + (s & 1) * 256 + (1 - role) * JH;
            if (tid < JH) {
                const int jl = tid, j = joff + jl;
                float xr = sbih[j], xz = sbih[EDIM + j], xn = sbih[2 * EDIM + j];
#pragma unroll
                for (int q = 0; q < 8; ++q) {
                    xr += gxp[q * GX_ROWS + jl];
                    xz += gxp[q * GX_ROWS + JH + jl];
                    xn += gxp[q * GX_ROWS + 2 * JH + jl];
                }
                float hr = sbhh[j], hz = sbhh[EDIM + j], hn_ = sbhh[2 * EDIM + j];
#pragma unroll
                for (int q = 0; q < 4; ++q) {
                    hr  += wap[q * WA_ROWS + 256 + jl];
                    hz  += wap[q * WA_ROWS + 384 + jl];
                    hn_ += wap[q * WA_ROWS + 512 + jl];
                }
                float r = 1.0f / (1.0f + __expf(-(xr + hr)));
                float z = 1.0f / (1.0f + __expf(-(xz + hz)));
                float n = tanhf(xn + r * hn_);
                float hnew = (1.0f - z) * n + z * h_s[j];
                h_s[j] = hnew;
                out[((size_t)b * SLEN + s) * EDIM + j] = hnew;

                const unsigned int want = (unsigned int)(s + 1);
                unsigned long long wrd = ((unsigned long long)want << 32)
                                       | (unsigned long long)__float_as_uint(hnew);
                __hip_atomic_store(myslot + jl, wrd, __ATOMIC_RELAXED, __HIP_MEMORY_SCOPE_AGENT);
                unsigned long long pw;
                for (;;) {
                    pw = __hip_atomic_load(pslot + jl, __ATOMIC_RELAXED, __HIP_MEMORY_SCOPE_AGENT);
                    if ((unsigned int)(pw >> 32) >= want) break;
                    __builtin_amdgcn_s_sleep(1);
                }
                h_s[(JH - joff) + jl] = __uint_as_float((unsigned int)pw);
            }
        }
        __syncthreads();                        // (7) full h ready
    }
}

extern "C" void kernel_launch(void* const* d_in, const int* in_sizes, int n_in,
                              void* d_out, int out_size, void* d_ws, size_t ws_size,
                              hipStream_t stream) {
    const float* signal = (const float*)d_in[0];
    const float* bases  = (const float*)d_in[1];
    const int*   mask   = (const int*)d_in[2];
    const float* Ww     = (const float*)d_in[3];
    const float* Wb     = (const float*)d_in[4];
    const float* lng    = (const float*)d_in[5];
    const float* lnb    = (const float*)d_in[6];
    const float* wih    = (const float*)d_in[7];
    const float* bih    = (const float*)d_in[8];
    const float* whh    = (const float*)d_in[9];
    const float* bhh    = (const float*)d_in[10];
    const float* hinit  = (const float*)d_in[11];
    float*       out    = (float*)d_out;

    const int B = in_sizes[0] / (TLEN * EDIM);   // 128

    // workspace: WA[2][256][640] | wihT[2][512][384] | payload u64[B][512]  (~3.4 MB)
    float* WA   = (float*)d_ws;
    float* wihT = WA + 2 * 256 * WA_ROWS;
    unsigned long long* payload = (unsigned long long*)(wihT + 2 * 512 * GX_ROWS);

    hipMemsetAsync(payload, 0, (size_t)B * 512 * sizeof(unsigned long long), stream);
    pack_fused_kernel<<<dim3(8, 4, 14), 256, 0, stream>>>(Ww, whh, wih, WA, wihT);
    gru_decoder_kernel<<<dim3(2 * B), dim3(NT), 0, stream>>>(
        signal, bases, mask, WA, Wb, lng, lnb, wihT, bih, bhh, hinit, payload, out, B, 0);
}